// Round 3
// baseline (465.484 us; speedup 1.0000x reference)
//
#include <hip/hip_runtime.h>

// LocalCorrelation via banded-GEMM MFMA (R5, resubmit after infra failure).
// out[b, dy*9+dx, h, w] = (1/C) * sum_c fs[b,c,h,w] * ft[b,c,h+dy-4,w+dx-4]
// B=16, C=256, H=W=96, RADIUS=4, D=9. fp32 in/out, f16 MFMA with fp32 accum.
//
// For fixed (b,h,dy), C[w,w'] = sum_c fs[c,w]*ft[c,w'] is a GEMM; the output
// is the 9-wide band out[dx,w] = C[w, w+dx-4]. Per 16-wide w-tile m: two
// 16x16x32 MFMAs per (dy, chunk) against ft subtiles covering
// w' in [16m-4,16m+12) and [16m+12,16m+28); dx = j-i or 16+j-i.
//
// No ds_read_b64_tr_b16 (R4's unverified assumption) and no inline asm.
// LDS subtiles are stored in MFMA-fragment order:
//   byte(k, wl) = (k>>2)*128 + wl*8 + (k&3)*2        (k = channel-in-chunk)
// so a fragment is 2 plain ds_read_b64 per lane (addr 128*(l>>4)+8*(l&15),
// +512 for the second k-half): 4 halves of ONE wl per read -> no row mixing;
// any fixed k-permutation is identical for A and B operands and cancels.
// Staging: item = 4 channels x 4 w = 4 float4 loads -> cvt_pkrtz -> 2
// contiguous uint4 LDS writes; 768 items/chunk = exactly 2 per thread.
//
// Block = (b, h, dyg of 3 dy), 6 waves = 6 w-tiles. LDS double-buffered
// 2 x 27648 B -> 2 blocks/CU. Halo cols + h-OOB rows zero-filled once.
// Batch->XCD grid swizzle kept (blockIdx&7 = XCD = b&7).

typedef _Float16 f16x8 __attribute__((ext_vector_type(8)));
typedef float f32x4 __attribute__((ext_vector_type(4)));

#define BB 16
#define CCH 256
#define HH 96
#define WW 96
#define HW (HH*WW)
#define DD 9
#define KC 32                 // channels per chunk = MFMA K
#define NCHUNK (CCH/KC)       // 8
#define NT 384                // 6 waves
#define SUBB 1024             // bytes per 16wl x 32k f16 subtile
#define NSUB_FT 21            // 3 rows x 7 subtiles
#define NSUB 27               // + 6 fs subtiles
#define BUFB (NSUB*SUBB)      // 27648 B per buffer
#define NFT 576               // ft quad-items per chunk (8cq*3row*24w4)

static __device__ __forceinline__ unsigned pk(float a, float b) {
    return __builtin_bit_cast(unsigned, __builtin_amdgcn_cvt_pkrtz(a, b));
}
static __device__ __forceinline__ f16x8 mk8(uint2 lo, uint2 hi) {
    uint4 u; u.x = lo.x; u.y = lo.y; u.z = hi.x; u.w = hi.y;
    return __builtin_bit_cast(f16x8, u);
}

__global__ __launch_bounds__(NT, 3)
void lcorr5(const float* __restrict__ fs, const float* __restrict__ ft,
            float* __restrict__ out) {
    __shared__ __align__(16) char smem[2][BUFB];

    // ---- grid decode: XCD (blockIdx&7) <-> batch; dyg fastest, then h
    const int x    = blockIdx.x;
    const int xcd  = x & 7;
    const int rest = x >> 3;        // 0..575
    const int bb   = rest & 1;
    const int td   = rest >> 1;     // 0..287 = h*3 + dyg
    const int b    = xcd + 8 * bb;
    const int h    = td / 3;
    const int dyg  = td - 3 * h;

    const int tid  = threadIdx.x;
    const int m    = tid >> 6;      // w-tile of this wave
    const int lane = tid & 63;
    const int lq   = lane >> 4;     // k-quad group
    const int lw   = lane & 15;     // wl within subtile

    // ---- zero both buffers once: w-halo + h-OOB rows stay 0 forever
    {
        unsigned* z = (unsigned*)&smem[0][0];
        #pragma unroll
        for (int i = 0; i < 36; ++i)     // 2*27648/4 = 13824 uints / 384 thr
            z[tid + i * NT] = 0u;
    }

    // ---- staging descriptors (hoisted): 2 quad-items per thread
    // item = (cq, [row,] w4): 4 channels (k=4cq..4cq+3) x 4 w (4w4..4w4+3)
    int gof[2]; int lof[2]; bool gv[2];
    const bool isft1 = (tid < NFT - NT);         // item 1: ft if tid<192
    #pragma unroll
    for (int k = 0; k < 2; ++k) {
        int idx = tid + k * NT;
        if (idx < NFT) {                         // ft item
            int cq  = idx / 72;                  // 72 = 3row*24w4
            int rem = idx - 72 * cq;
            int row = rem / 24;
            int w4  = rem - 24 * row;
            int hp  = h + 3 * dyg + row - 4;
            bool v  = (hp >= 0 && hp < HH);
            gv[k]   = v;
            gof[k]  = 4 * cq * HW + (v ? hp : 0) * WW + 4 * w4;
            int wp  = 4 * w4 + 4;                // w' + RAD
            int t   = wp >> 4;
            int wl  = wp & 15;
            lof[k]  = (row * 7 + t) * SUBB + cq * 128 + 8 * wl;
        } else {                                 // fs item
            int j   = idx - NFT;
            int cq  = j / 24;
            int w4  = j - 24 * cq;
            gv[k]   = true;
            gof[k]  = 4 * cq * HW + h * WW + 4 * w4;
            int t   = w4 >> 2;
            int wl  = (4 * w4) & 15;
            lof[k]  = (NSUB_FT + t) * SUBB + cq * 128 + 8 * wl;
        }
    }

    const float* ftp = ft + (size_t)b * CCH * HW;
    const float* fsp = fs + (size_t)b * CCH * HW;

    f32x4 acc[3][2];
    #pragma unroll
    for (int i = 0; i < 3; ++i) {
        acc[i][0] = (f32x4){0.f, 0.f, 0.f, 0.f};
        acc[i][1] = (f32x4){0.f, 0.f, 0.f, 0.f};
    }

    // ---- prologue: stage chunk 0 into buffer 0
    {
        float4 st[2][4];
        #pragma unroll
        for (int k = 0; k < 2; ++k) {
            const float* sp = (k == 0 || isft1) ? ftp : fsp;
            #pragma unroll
            for (int q = 0; q < 4; ++q)
                st[k][q] = gv[k] ? *(const float4*)(sp + gof[k] + q * HW)
                                 : make_float4(0.f, 0.f, 0.f, 0.f);
        }
        __syncthreads();   // zero-init complete before cross-thread stores
        #pragma unroll
        for (int k = 0; k < 2; ++k) {
            uint4 lo, hi;
            lo.x = pk(st[k][0].x, st[k][1].x); lo.y = pk(st[k][2].x, st[k][3].x);
            lo.z = pk(st[k][0].y, st[k][1].y); lo.w = pk(st[k][2].y, st[k][3].y);
            hi.x = pk(st[k][0].z, st[k][1].z); hi.y = pk(st[k][2].z, st[k][3].z);
            hi.z = pk(st[k][0].w, st[k][1].w); hi.w = pk(st[k][2].w, st[k][3].w);
            char* d = &smem[0][0] + lof[k];
            *(uint4*)(d)      = lo;
            *(uint4*)(d + 16) = hi;
        }
        ftp += KC * HW; fsp += KC * HW;
    }

    for (int ch = 0; ch < NCHUNK; ++ch) {
        __syncthreads();                 // buffer p fully staged
        const int p = ch & 1;
        const bool more = (ch + 1 < NCHUNK);
        float4 st[2][4];
        if (more) {                      // issue next-chunk loads early
            #pragma unroll
            for (int k = 0; k < 2; ++k) {
                const float* sp = (k == 0 || isft1) ? ftp : fsp;
                #pragma unroll
                for (int q = 0; q < 4; ++q)
                    st[k][q] = gv[k] ? *(const float4*)(sp + gof[k] + q * HW)
                                     : make_float4(0.f, 0.f, 0.f, 0.f);
            }
        }

        // ---- compute: 14 ds_read_b64 + 6 MFMA from buffer p
        const char* bp = &smem[p][0];
        const char* vA = bp + (NSUB_FT + m) * SUBB + 128 * lq + 8 * lw;
        const char* vB = bp + m * SUBB + 128 * lq + 8 * lw;
        const f16x8 Af = mk8(*(const uint2*)(vA), *(const uint2*)(vA + 512));
        #pragma unroll
        for (int dyl = 0; dyl < 3; ++dyl) {
            #pragma unroll
            for (int t01 = 0; t01 < 2; ++t01) {
                const char* q = vB + dyl * 7168 + t01 * 1024;
                const f16x8 Bf = mk8(*(const uint2*)(q), *(const uint2*)(q + 512));
                acc[dyl][t01] = __builtin_amdgcn_mfma_f32_16x16x32_f16(
                    Af, Bf, acc[dyl][t01], 0, 0, 0);
            }
        }

        if (more) {                      // stage into buffer p^1
            #pragma unroll
            for (int k = 0; k < 2; ++k) {
                uint4 lo, hi;
                lo.x = pk(st[k][0].x, st[k][1].x); lo.y = pk(st[k][2].x, st[k][3].x);
                lo.z = pk(st[k][0].y, st[k][1].y); lo.w = pk(st[k][2].y, st[k][3].y);
                hi.x = pk(st[k][0].z, st[k][1].z); hi.y = pk(st[k][2].z, st[k][3].z);
                hi.z = pk(st[k][0].w, st[k][1].w); hi.w = pk(st[k][2].w, st[k][3].w);
                char* d = &smem[p ^ 1][0] + lof[k];
                *(uint4*)(d)      = lo;
                *(uint4*)(d + 16) = hi;
            }
            ftp += KC * HW; fsp += KC * HW;
        }
    }

    // ---- epilogue: band decode + scaled scalar stores
    // D[i][j]: i = 4*(lane>>4)+reg (A/fs -> w), j = lane&15 (B/ft -> w')
    // tile0: w' = 16m-4+j  -> dx = j-i     (valid 0..8)
    // tile1: w' = 16m+12+j -> dx = 16+j-i  (valid 1..8)
    const float scale = 1.0f / (float)CCH;
    const int j = lane & 15;
    #pragma unroll
    for (int dyl = 0; dyl < 3; ++dyl) {
        const int dy = 3 * dyg + dyl;
        #pragma unroll
        for (int r = 0; r < 4; ++r) {
            const int i = 4 * lq + r;
            const int w = 16 * m + i;
            const int d0 = j - i;
            if ((unsigned)d0 < DD)
                out[(((size_t)b * (DD * DD) + dy * DD + d0) * HH + h) * WW + w]
                    = acc[dyl][0][r] * scale;
            const int d1 = 16 + j - i;
            if (d1 <= 8)
                out[(((size_t)b * (DD * DD) + dy * DD + d1) * HH + h) * WW + w]
                    = acc[dyl][1][r] * scale;
        }
    }
}

extern "C" void kernel_launch(void* const* d_in, const int* in_sizes, int n_in,
                              void* d_out, int out_size, void* d_ws, size_t ws_size,
                              hipStream_t stream) {
    const float* fs = (const float*)d_in[0];
    const float* ft = (const float*)d_in[1];
    float* out = (float*)d_out;
    dim3 grid(BB * HH * 3);   // 4608 blocks
    lcorr5<<<grid, dim3(NT), 0, stream>>>(fs, ft, out);
}